// Round 2
// baseline (244.533 us; speedup 1.0000x reference)
//
#include <hip/hip_runtime.h>

#define N 192
#define AN 383          // 2N-1
#define ASTRIDE 384     // padded row stride for A (in float2)
#define NSPLIT 16       // dy-dimension split across blocks
#define DYPER (N / NSPLIT)  // 12

// ---------------------------------------------------------------------------
// Kernel 1: build physics kernel A (383x383 complex, interleaved) and
// interleave the input field into W (192x192 complex).
// ---------------------------------------------------------------------------
__global__ __launch_bounds__(256) void prep_kernel(const float* __restrict__ fr,
                                                   const float* __restrict__ fi,
                                                   const float* __restrict__ zp,
                                                   float2* __restrict__ A,
                                                   float2* __restrict__ W) {
    int idx = blockIdx.x * 256 + threadIdx.x;
    float z = zp[0];
    if (idx < AN * AN) {
        int r = idx / AN;
        int c = idx - r * AN;
        const float X0 = 191.00005f;           // 0.5*(2*192 + 1e-4) - 1
        float xr = (float)r - X0;
        float yc = (float)c - X0;
        float r2 = xr * xr + yc * yc;
        float R  = sqrtf(r2 + z * z);
        float RHO = sqrtf(r2);
        float Kfac = cosf(atan2f(RHO, z));     // obliquity cos(theta)
        float amp = Kfac / R;
        const float k = 12.566371f;            // 2*pi/0.5 in fp32
        float ph = k * R;
        float sv, cv;
        sincosf(ph, &sv, &cv);                 // sv=sin, cv=cos
        A[r * ASTRIDE + c] = make_float2(amp * cv, amp * sv);
    }
    if (idx < N * N) {
        W[idx] = make_float2(fr[idx], fi[idx]);
    }
}

// ---------------------------------------------------------------------------
// Kernel 2: direct complex cross-correlation, VALID.
//   C[y,x] = sum_{dy,dx} A[y+dy, x+dx] * W[dy,dx]   (complex multiply)
// Tile: 64 output cols x 16 output rows per block (256 thr).
// dy-reduction split NSPLIT ways across blockIdx.z -> partials.
// ---------------------------------------------------------------------------
__global__ __launch_bounds__(256) void conv_kernel(const float2* __restrict__ A,
                                                   const float2* __restrict__ W,
                                                   float2* __restrict__ part) {
    __shared__ float2 lds_A[16][256];   // 16 A rows x 255 used cols
    __shared__ float2 lds_W[N];         // one filter row

    const int tid  = threadIdx.x;
    const int lane = tid & 63;
    const int wv   = tid >> 6;          // wave id 0..3
    const int x0   = blockIdx.x * 64;
    const int y0   = blockIdx.y * 16;
    const int dy0  = blockIdx.z * DYPER;

    float2 acc[4];
    #pragma unroll
    for (int j = 0; j < 4; ++j) acc[j] = make_float2(0.f, 0.f);

    for (int dy = dy0; dy < dy0 + DYPER; ++dy) {
        __syncthreads();   // protect previous iteration's reads
        // stage one filter row
        if (tid < N) lds_W[tid] = W[dy * N + tid];
        // stage 16 A rows, 255 cols each, starting at (y0+dy, x0)
        const float2* arow = A + (y0 + dy) * ASTRIDE + x0;
        if (tid < 255) {
            #pragma unroll
            for (int row = 0; row < 16; ++row)
                lds_A[row][tid] = arow[row * ASTRIDE + tid];
        }
        __syncthreads();

        #pragma unroll 4
        for (int dx = 0; dx < N; ++dx) {
            float2 wvv = lds_W[dx];
            #pragma unroll
            for (int j = 0; j < 4; ++j) {
                float2 a = lds_A[wv * 4 + j][lane + dx];
                acc[j].x = fmaf(a.x, wvv.x, acc[j].x);
                acc[j].x = fmaf(-a.y, wvv.y, acc[j].x);
                acc[j].y = fmaf(a.x, wvv.y, acc[j].y);
                acc[j].y = fmaf(a.y, wvv.x, acc[j].y);
            }
        }
    }

    const int split = blockIdx.z;
    #pragma unroll
    for (int j = 0; j < 4; ++j) {
        int y = y0 + wv * 4 + j;
        int x = x0 + lane;
        part[split * (N * N) + y * N + x] = acc[j];
    }
}

// ---------------------------------------------------------------------------
// Kernel 3: sum the NSPLIT partials, write REAL PART of the flipped output.
// (Expected output = float32 coercion of the complex result = real part.)
// ---------------------------------------------------------------------------
__global__ __launch_bounds__(256) void reduce_kernel(const float2* __restrict__ part,
                                                     float* __restrict__ out) {
    int idx = blockIdx.x * 256 + threadIdx.x;   // < N*N
    int y = idx / N;
    int x = idx - y * N;
    float sr = 0.f;
    #pragma unroll
    for (int sp = 0; sp < NSPLIT; ++sp) {
        sr += part[sp * (N * N) + idx].x;
    }
    out[(N - 1 - y) * N + (N - 1 - x)] = sr;
}

extern "C" void kernel_launch(void* const* d_in, const int* in_sizes, int n_in,
                              void* d_out, int out_size, void* d_ws, size_t ws_size,
                              hipStream_t stream) {
    const float* fr = (const float*)d_in[0];   // input_real, 192*192
    const float* fi = (const float*)d_in[1];   // input_imag, 192*192
    const float* zp = (const float*)d_in[2];   // z scalar

    float2* A    = (float2*)d_ws;              // 147072 float2
    float2* W    = A + AN * ASTRIDE;           // 36864 float2
    float2* part = W + N * N;                  // NSPLIT * 36864 float2
    // total ws use: (147072 + 36864 + 16*36864) * 8 B ~= 6.2 MB

    prep_kernel<<<(AN * AN + 255) / 256, 256, 0, stream>>>(fr, fi, zp, A, W);
    conv_kernel<<<dim3(N / 64, N / 16, NSPLIT), 256, 0, stream>>>(A, W, part);
    reduce_kernel<<<(N * N + 255) / 256, 256, 0, stream>>>(part, (float*)d_out);
}

// Round 3
// 131.385 us; speedup vs baseline: 1.8612x; 1.8612x over previous
//
#include <hip/hip_runtime.h>

#define N 192
#define AN 383          // 2N-1
#define ASTRIDE 384     // padded row stride for A (in float2)
#define YT 8            // output rows per block (4 waves x 2 rows)
#define DYPER 6         // dy values per block
#define NSPLIT 32       // 192 / DYPER
#define NROWS (YT + DYPER - 1)   // 13 staged A rows

// ---------------------------------------------------------------------------
// Kernel 1: build physics kernel A (383x383 complex, interleaved).
// ---------------------------------------------------------------------------
__global__ __launch_bounds__(256) void prep_kernel(const float* __restrict__ zp,
                                                   float2* __restrict__ A) {
    int idx = blockIdx.x * 256 + threadIdx.x;
    float z = zp[0];
    if (idx < AN * AN) {
        int r = idx / AN;
        int c = idx - r * AN;
        const float X0 = 191.00005f;           // 0.5*(2*192 + 1e-4) - 1
        float xr = (float)r - X0;
        float yc = (float)c - X0;
        float r2 = xr * xr + yc * yc;
        float R  = sqrtf(r2 + z * z);
        float RHO = sqrtf(r2);
        float Kfac = cosf(atan2f(RHO, z));     // obliquity cos(theta)
        float amp = Kfac / R;
        const float k = 12.566371f;            // 2*pi/0.5
        float ph = k * R;
        float sv, cv;
        sincosf(ph, &sv, &cv);
        A[r * ASTRIDE + c] = make_float2(amp * cv, amp * sv);
    }
}

// ---------------------------------------------------------------------------
// Kernel 2: real part of the complex cross-correlation, VALID.
//   Cr[y,x] = sum_{dy,dx} Ar[y+dy,x+dx]*Wr[dy,dx] - Ai[y+dy,x+dx]*Wi[dy,dx]
// Wave = one full output row span (64 lanes x 3 consecutive x each).
// Register rotation over dx: 1 new ds_read_b64 per row per dx -> 6 FMA.
// Block: 8 y-rows x 192 x, dy-chunk of 6. 768 blocks = 3/CU, one round.
// ---------------------------------------------------------------------------
__global__ __launch_bounds__(256, 3) void conv_kernel(const float2* __restrict__ A,
                                                      const float* __restrict__ fr,
                                                      const float* __restrict__ fi,
                                                      float* __restrict__ part) {
    __shared__ float2 ldsA[NROWS][ASTRIDE];   // 13*384*8 = 39936 B
    __shared__ float2 ldsW[DYPER][N];         // 6*192*8  =  9216 B

    const int tid = threadIdx.x;
    const int L   = tid & 63;
    const int wv  = tid >> 6;
    const int dy0 = blockIdx.x * DYPER;
    const int y0  = blockIdx.y * YT;
    const int u0  = y0 + dy0;                 // first staged A row

    // stage 13 A rows (coalesced: consecutive tid -> consecutive col)
    for (int i = tid; i < NROWS * AN; i += 256) {
        int row = i / AN;
        int col = i - row * AN;
        ldsA[row][col] = A[(u0 + row) * ASTRIDE + col];
    }
    // stage 6 W rows, interleaving fr/fi
    for (int i = tid; i < DYPER * N; i += 256) {
        int r = i / N, c = i - r * N;
        ldsW[r][c] = make_float2(fr[(dy0 + r) * N + c], fi[(dy0 + r) * N + c]);
    }
    __syncthreads();

    float acc[2][3] = {{0.f,0.f,0.f},{0.f,0.f,0.f}};

    for (int q = 0; q < DYPER; ++q) {
        const int r0 = q + wv * 2;            // LDS slot of A row for rr=0
        const float2* __restrict__ w = ldsW[q];
        // rotation registers: window of 3 consecutive cols per row
        float2 A0[2], A1[2], A2[2];
        #pragma unroll
        for (int rr = 0; rr < 2; ++rr) {
            A0[rr] = ldsA[r0 + rr][3*L + 0];
            A1[rr] = ldsA[r0 + rr][3*L + 1];
            A2[rr] = ldsA[r0 + rr][3*L + 2];
        }
        for (int d = 0; d < N; d += 3) {
            float2 w0 = w[d];
            #pragma unroll
            for (int rr = 0; rr < 2; ++rr) {
                acc[rr][0] = fmaf(A0[rr].x,  w0.x, acc[rr][0]);
                acc[rr][0] = fmaf(A0[rr].y, -w0.y, acc[rr][0]);
                acc[rr][1] = fmaf(A1[rr].x,  w0.x, acc[rr][1]);
                acc[rr][1] = fmaf(A1[rr].y, -w0.y, acc[rr][1]);
                acc[rr][2] = fmaf(A2[rr].x,  w0.x, acc[rr][2]);
                acc[rr][2] = fmaf(A2[rr].y, -w0.y, acc[rr][2]);
                A0[rr] = ldsA[r0 + rr][3*L + d + 3];   // refill dead reg
            }
            float2 w1 = w[d + 1];
            #pragma unroll
            for (int rr = 0; rr < 2; ++rr) {
                acc[rr][0] = fmaf(A1[rr].x,  w1.x, acc[rr][0]);
                acc[rr][0] = fmaf(A1[rr].y, -w1.y, acc[rr][0]);
                acc[rr][1] = fmaf(A2[rr].x,  w1.x, acc[rr][1]);
                acc[rr][1] = fmaf(A2[rr].y, -w1.y, acc[rr][1]);
                acc[rr][2] = fmaf(A0[rr].x,  w1.x, acc[rr][2]);
                acc[rr][2] = fmaf(A0[rr].y, -w1.y, acc[rr][2]);
                A1[rr] = ldsA[r0 + rr][3*L + d + 4];
            }
            float2 w2 = w[d + 2];
            #pragma unroll
            for (int rr = 0; rr < 2; ++rr) {
                acc[rr][0] = fmaf(A2[rr].x,  w2.x, acc[rr][0]);
                acc[rr][0] = fmaf(A2[rr].y, -w2.y, acc[rr][0]);
                acc[rr][1] = fmaf(A0[rr].x,  w2.x, acc[rr][1]);
                acc[rr][1] = fmaf(A0[rr].y, -w2.y, acc[rr][1]);
                acc[rr][2] = fmaf(A1[rr].x,  w2.x, acc[rr][2]);
                acc[rr][2] = fmaf(A1[rr].y, -w2.y, acc[rr][2]);
                A2[rr] = ldsA[r0 + rr][3*L + d + 5];
            }
        }
        // max col touched: 3*63 + 189 + 5 = 383 < ASTRIDE  (value unused)
    }

    #pragma unroll
    for (int rr = 0; rr < 2; ++rr) {
        #pragma unroll
        for (int c = 0; c < 3; ++c) {
            int y = y0 + wv * 2 + rr;
            int x = 3 * L + c;
            part[blockIdx.x * (N * N) + y * N + x] = acc[rr][c];
        }
    }
}

// ---------------------------------------------------------------------------
// Kernel 3: sum the NSPLIT dy-chunk partials, write flipped real output.
// ---------------------------------------------------------------------------
__global__ __launch_bounds__(256) void reduce_kernel(const float* __restrict__ part,
                                                     float* __restrict__ out) {
    int idx = blockIdx.x * 256 + threadIdx.x;   // < N*N
    int y = idx / N;
    int x = idx - y * N;
    float s = 0.f;
    #pragma unroll
    for (int sp = 0; sp < NSPLIT; ++sp) {
        s += part[sp * (N * N) + idx];
    }
    out[(N - 1 - y) * N + (N - 1 - x)] = s;
}

extern "C" void kernel_launch(void* const* d_in, const int* in_sizes, int n_in,
                              void* d_out, int out_size, void* d_ws, size_t ws_size,
                              hipStream_t stream) {
    const float* fr = (const float*)d_in[0];   // input_real, 192*192
    const float* fi = (const float*)d_in[1];   // input_imag, 192*192
    const float* zp = (const float*)d_in[2];   // z scalar

    float2* A    = (float2*)d_ws;              // 147072 float2 = 1.18 MB
    float*  part = (float*)(A + AN * ASTRIDE); // NSPLIT * 36864 f32 = 4.72 MB

    prep_kernel<<<(AN * AN + 255) / 256, 256, 0, stream>>>(zp, A);
    conv_kernel<<<dim3(NSPLIT, N / YT), 256, 0, stream>>>(A, fr, fi, part);
    reduce_kernel<<<(N * N + 255) / 256, 256, 0, stream>>>(part, (float*)d_out);
}